// Round 16
// baseline (70.876 us; speedup 1.0000x reference)
//
#include <hip/hip_runtime.h>
#include <hip/hip_bf16.h>
#include <math.h>

// Problem constants
#define BB   256
#define INW  512
#define HH   1024
#define OUTW 512
#define SS   512
#define WD   256
#define P_READ  262
#define P_WRITE 774
#define RW_LD   1056   // 272 (read pad) + 784 (write pad)
#define W_OFF   272
#define H2LD 1056      // h2 row: 1024 h | 1 one | 31 zeros
#define M1LD 1056      // M1ext row: 1024 j | 1 Bterm | 31 zeros

typedef __attribute__((ext_vector_type(8))) short bf16x8;
typedef __attribute__((ext_vector_type(4))) float f32x4;

__device__ __forceinline__ float sigmoidf(float x) { return 1.f / (1.f + expf(-x)); }
__device__ __forceinline__ float softplusf(float x) { return (x > 20.f) ? x : log1pf(expf(x)); }
__device__ __forceinline__ void st_bf4f(__hip_bfloat16* d, float a, float b, float c, float e) {
    union { ushort4 u4; __hip_bfloat16 h[4]; } u;
    u.h[0] = __float2bfloat16(a); u.h[1] = __float2bfloat16(b);
    u.h[2] = __float2bfloat16(c); u.h[3] = __float2bfloat16(e);
    *reinterpret_cast<ushort4*>(d) = u.u4;
}
__device__ __forceinline__ float wave_sum(float v) {
    #pragma unroll
    for (int off = 32; off > 0; off >>= 1) v += __shfl_down(v, off, 64);
    return v;
}

// ================= K1: convert/pack + WkT gather + mem norms + biases =================
#define N_WIH (3072*512)
#define N_WRW (RW_LD*1024)
#define N_WO  (512*1280)
#define N_X   (256*512)
#define N_MB  (512*256)
#define N_MT  (256*512)
#define N_WKT (2*1024*256)
#define N_BIA 3072
#define N_BRW RW_LD
#define N_TOT (N_WIH+N_WRW+N_WO+N_X+N_MB+N_MT+N_WKT+N_BIA+N_BRW)
#define NB_CVT ((N_TOT/4 + 255) / 256)

__global__ __launch_bounds__(256)
void convert_all(const float* __restrict__ W_ih, const float* __restrict__ b_ih,
                 const float* __restrict__ b_hh,
                 const float* __restrict__ W_read, const float* __restrict__ b_read,
                 const float* __restrict__ W_write, const float* __restrict__ b_write,
                 const float* __restrict__ W_out, const float* __restrict__ x,
                 const float* __restrict__ mem,
                 __hip_bfloat16* __restrict__ Wih_c, __hip_bfloat16* __restrict__ Wrw_p,
                 __hip_bfloat16* __restrict__ Wo_b, __hip_bfloat16* __restrict__ x_b,
                 __hip_bfloat16* __restrict__ mem_b, __hip_bfloat16* __restrict__ memT_b,
                 __hip_bfloat16* __restrict__ WkT,
                 float* __restrict__ bias_c, float* __restrict__ bias_rw,
                 float* __restrict__ mem_norm)
{
    if (blockIdx.x >= NB_CVT) {
        __shared__ float red[4];
        int s = blockIdx.x - NB_CVT;
        float v = mem[(size_t)s * WD + threadIdx.x];
        float vv = wave_sum(v * v);
        if ((threadIdx.x & 63) == 0) red[threadIdx.x >> 6] = vv;
        __syncthreads();
        if (threadIdx.x == 0)
            mem_norm[s] = fmaxf(sqrtf(red[0] + red[1] + red[2] + red[3]), 1e-8f);
        return;
    }
    long i = ((long)blockIdx.x * 256 + threadIdx.x) * 4;
    if (i >= N_TOT) return;
    if (i < N_WIH) {   // compact i|g|o rows, first 512 cols
        int r = (int)(i >> 9), c = (int)(i & 511);
        int sr = r < 1024 ? r : r + 1024;
        float4 v = *reinterpret_cast<const float4*>(W_ih + (size_t)sr * 768 + c);
        st_bf4f(Wih_c + i, v.x, v.y, v.z, v.w);
        return;
    }
    i -= N_WIH;
    if (i < N_WRW) {
        int r = (int)(i >> 10), c = (int)(i & 1023);
        float4 v = make_float4(0.f, 0.f, 0.f, 0.f);
        if (r < W_OFF) { if (r < P_READ) v = *reinterpret_cast<const float4*>(W_read + (size_t)r * 1024 + c); }
        else { int wr = r - W_OFF; if (wr < P_WRITE) v = *reinterpret_cast<const float4*>(W_write + (size_t)wr * 1024 + c); }
        st_bf4f(Wrw_p + i, v.x, v.y, v.z, v.w);
        return;
    }
    i -= N_WRW;
    if (i < N_WO) {
        float4 v = *reinterpret_cast<const float4*>(W_out + i);
        st_bf4f(Wo_b + i, v.x, v.y, v.z, v.w);
        return;
    }
    i -= N_WO;
    if (i < N_X) {
        float4 v = *reinterpret_cast<const float4*>(x + i);
        st_bf4f(x_b + i, v.x, v.y, v.z, v.w);
        return;
    }
    i -= N_X;
    if (i < N_MB) {
        float4 v = *reinterpret_cast<const float4*>(mem + i);
        st_bf4f(mem_b + i, v.x, v.y, v.z, v.w);
        return;
    }
    i -= N_MB;
    if (i < N_MT) {   // memT gather
        int w = (int)(i >> 9), s = (int)(i & 511);
        st_bf4f(memT_b + i, mem[(size_t)s * 256 + w], mem[(size_t)(s + 1) * 256 + w],
                mem[(size_t)(s + 2) * 256 + w], mem[(size_t)(s + 3) * 256 + w]);
        return;
    }
    i -= N_MT;
    if (i < N_WKT) {  // WkT[mat][j][w] = Wkey[w][j]  (output-coalesced gather)
        int mat = (int)(i >> 18);          // i / 262144
        int ii = (int)(i & 262143);
        int j = ii >> 8, w0 = ii & 255;
        const float* src = (mat ? W_write : W_read);
        st_bf4f(WkT + i, src[(size_t)(w0 + 0) * 1024 + j], src[(size_t)(w0 + 1) * 1024 + j],
                src[(size_t)(w0 + 2) * 1024 + j], src[(size_t)(w0 + 3) * 1024 + j]);
        return;
    }
    i -= N_WKT;
    if (i < N_BIA) {
        #pragma unroll
        for (int u = 0; u < 4; ++u) {
            long r = i + u;
            long sr = r < 1024 ? r : r + 1024;
            bias_c[r] = b_ih[sr] + b_hh[sr];
        }
        return;
    }
    i -= N_BIA;
    {
        #pragma unroll
        for (int u = 0; u < 4; ++u) {
            long r = i + u;
            float v = 0.f;
            if (r < W_OFF) { if (r < P_READ) v = b_read[r]; }
            else { long wr = r - W_OFF; if (wr < P_WRITE) v = b_write[wr]; }
            bias_rw[r] = v;
        }
    }
}

// ================= K2: gates GEMM+LSTM -> h2 | M1 build | Bterm | pads =================
#define S2_GATES 1024
#define S2_M1    4096    // 2 mats x 32 s-tiles x 64 j-tiles
#define S2_BT    16
#define S2_H2P   1
#define S2_M1P   16
#define S2_TOT   (S2_GATES + S2_M1 + S2_BT + S2_H2P + S2_M1P)

__global__ __launch_bounds__(64)
void k_stage2(const __hip_bfloat16* __restrict__ x_b,
              const __hip_bfloat16* __restrict__ Wih_c,
              const float* __restrict__ bias_c,
              const __hip_bfloat16* __restrict__ mem_b,
              const __hip_bfloat16* __restrict__ WkT,
              const float* __restrict__ b_read, const float* __restrict__ b_write,
              const float* __restrict__ mem_norm,
              __hip_bfloat16* __restrict__ h2, __hip_bfloat16* __restrict__ M1ext)
{
    const int bid = blockIdx.x;
    const int lane = threadIdx.x;
    const int r = lane & 15, q = lane >> 4;

    if (bid < S2_GATES) {
        const int bn = (bid & 63) * 16;    // j tile
        const int bm = (bid >> 6) * 16;    // b tile
        const __hip_bfloat16* ap = x_b + (size_t)(bm + r) * INW + q * 8;
        const __hip_bfloat16* bi = Wih_c + (size_t)(bn + r) * INW + q * 8;
        const __hip_bfloat16* bg = bi + (size_t)1024 * INW;
        const __hip_bfloat16* bo = bi + (size_t)2048 * INW;
        f32x4 ai = {0.f,0.f,0.f,0.f}, ag = ai, ao = ai;
        #pragma unroll
        for (int k = 0; k < INW; k += 32) {
            bf16x8 a = *reinterpret_cast<const bf16x8*>(ap + k);
            ai = __builtin_amdgcn_mfma_f32_16x16x32_bf16(a, *reinterpret_cast<const bf16x8*>(bi + k), ai, 0, 0, 0);
            ag = __builtin_amdgcn_mfma_f32_16x16x32_bf16(a, *reinterpret_cast<const bf16x8*>(bg + k), ag, 0, 0, 0);
            ao = __builtin_amdgcn_mfma_f32_16x16x32_bf16(a, *reinterpret_cast<const bf16x8*>(bo + k), ao, 0, 0, 0);
        }
        const int j = bn + r;
        const float bii = bias_c[j], big = bias_c[1024 + j], bio = bias_c[2048 + j];
        #pragma unroll
        for (int jj = 0; jj < 4; ++jj) {
            int b = bm + q * 4 + jj;
            float c = sigmoidf(ai[jj] + bii) * tanhf(ag[jj] + big);
            h2[(size_t)b * H2LD + j] = __float2bfloat16(sigmoidf(ao[jj] + bio) * tanhf(c));
        }
        return;
    }
    if (bid < S2_GATES + S2_M1) {
        // M1[mat*512+s][j] = (sum_w mem[s,w] * Wkey[w,j]) / ||mem_s||
        int m = bid - S2_GATES;
        int mat = m >> 11;                 // m / 2048
        int t = m & 2047;
        int st = t >> 6, jt = t & 63;
        const int bm = st * 16, bn = jt * 16;
        const __hip_bfloat16* ap = mem_b + (size_t)(bm + r) * WD + q * 8;
        const __hip_bfloat16* bp = WkT + (size_t)(mat * 1024 + bn + r) * WD + q * 8;
        f32x4 acc = {0.f,0.f,0.f,0.f};
        #pragma unroll
        for (int k = 0; k < WD; k += 32)
            acc = __builtin_amdgcn_mfma_f32_16x16x32_bf16(
                *reinterpret_cast<const bf16x8*>(ap + k),
                *reinterpret_cast<const bf16x8*>(bp + k), acc, 0, 0, 0);
        #pragma unroll
        for (int jj = 0; jj < 4; ++jj) {
            int srow = bm + q * 4 + jj;
            float inv = 1.f / mem_norm[srow];
            M1ext[(size_t)(mat * 512 + srow) * M1LD + bn + r] = __float2bfloat16(acc[jj] * inv);
        }
        return;
    }
    if (bid < S2_GATES + S2_M1 + S2_BT) {
        // Bterm: M1ext[row][1024] = (mem[s,:] . bias_key) / ||mem_s||
        int gid = (bid - S2_GATES - S2_M1) * 64 + lane;   // 0..1023
        int mat = gid >> 9, s = gid & 511;
        const float* bias = mat ? b_write : b_read;
        const __hip_bfloat16* mrow = mem_b + (size_t)s * WD;
        float acc = 0.f;
        #pragma unroll 8
        for (int w = 0; w < WD; ++w)
            acc += __bfloat162float(mrow[w]) * bias[w];
        M1ext[(size_t)gid * M1LD + 1024] = __float2bfloat16(acc / mem_norm[s]);
        return;
    }
    if (bid < S2_GATES + S2_M1 + S2_BT + S2_H2P) {
        // h2 pad: col 1024 = 1, cols 1025..1055 = 0
        for (int idx = lane; idx < 256 * 32; idx += 64) {
            int row = idx >> 5, c = idx & 31;
            h2[(size_t)row * H2LD + 1024 + c] = __float2bfloat16(c == 0 ? 1.f : 0.f);
        }
        return;
    }
    {
        // M1 pad: cols 1025..1055 = 0
        int row = (bid - (S2_GATES + S2_M1 + S2_BT + S2_H2P)) * 64 + lane;
        #pragma unroll
        for (int c = 1025; c < 1056; ++c)
            M1ext[(size_t)row * M1LD + c] = __float2bfloat16(0.f);
    }
}

// ================= K3: rpwp GEMM | out_h GEMM | num GEMM =================
__global__ __launch_bounds__(64)
void k_stage3(const __hip_bfloat16* __restrict__ h2,
              const __hip_bfloat16* __restrict__ Wrw_p,
              const __hip_bfloat16* __restrict__ Wo_b,
              const __hip_bfloat16* __restrict__ M1ext,
              const float* __restrict__ bias_rw, const float* __restrict__ b_out,
              float* __restrict__ rpwp, float* __restrict__ out,
              float* __restrict__ numd)
{
    const int bid = blockIdx.x;
    const int lane = threadIdx.x;
    const int r = lane & 15, q = lane >> 4;

    if (bid < 1056) {
        const int nt = bid % 66, mt = bid / 66;
        const int bm = mt * 16, bn = nt * 16;
        const __hip_bfloat16* ap = h2 + (size_t)(bm + r) * H2LD + q * 8;
        const __hip_bfloat16* bp = Wrw_p + (size_t)(bn + r) * HH + q * 8;
        f32x4 a0 = {0.f,0.f,0.f,0.f}, a1 = a0;
        #pragma unroll 8
        for (int k = 0; k < 512; k += 32) {
            a0 = __builtin_amdgcn_mfma_f32_16x16x32_bf16(
                *reinterpret_cast<const bf16x8*>(ap + k),
                *reinterpret_cast<const bf16x8*>(bp + k), a0, 0, 0, 0);
            a1 = __builtin_amdgcn_mfma_f32_16x16x32_bf16(
                *reinterpret_cast<const bf16x8*>(ap + 512 + k),
                *reinterpret_cast<const bf16x8*>(bp + 512 + k), a1, 0, 0, 0);
        }
        const int col = bn + r;
        const float bv = bias_rw[col];
        #pragma unroll
        for (int j = 0; j < 4; ++j) {
            int m = bm + q * 4 + j;
            rpwp[(size_t)m * RW_LD + col] = a0[j] + a1[j] + bv;
        }
    } else if (bid < 1568) {
        const int o = bid - 1056;
        const int nt = o & 31, mt = o >> 5;
        const int bm = mt * 16, bn = nt * 16;
        const __hip_bfloat16* ap = h2 + (size_t)(bm + r) * H2LD + q * 8;
        const __hip_bfloat16* bp = Wo_b + (size_t)(bn + r) * 1280 + q * 8;
        f32x4 a0 = {0.f,0.f,0.f,0.f}, a1 = a0;
        #pragma unroll 8
        for (int k = 0; k < 512; k += 32) {
            a0 = __builtin_amdgcn_mfma_f32_16x16x32_bf16(
                *reinterpret_cast<const bf16x8*>(ap + k),
                *reinterpret_cast<const bf16x8*>(bp + k), a0, 0, 0, 0);
            a1 = __builtin_amdgcn_mfma_f32_16x16x32_bf16(
                *reinterpret_cast<const bf16x8*>(ap + 512 + k),
                *reinterpret_cast<const bf16x8*>(bp + 512 + k), a1, 0, 0, 0);
        }
        const int col = bn + r;
        const float bv = b_out[col];
        #pragma unroll
        for (int j = 0; j < 4; ++j) {
            int m = bm + q * 4 + j;
            out[(size_t)m * OUTW + col] = a0[j] + a1[j] + bv;
        }
    } else {
        // num = h2 @ M1ext^T  -> numd[b][s'] (s'<512 read, >=512 write), /||mem_s|| folded
        const int o = bid - 1568;
        const int nt = o & 63, mt = o >> 6;
        const int bm = mt * 16, bn = nt * 16;
        const __hip_bfloat16* ap = h2 + (size_t)(bm + r) * H2LD + q * 8;
        const __hip_bfloat16* bp = M1ext + (size_t)(bn + r) * M1LD + q * 8;
        f32x4 a0 = {0.f,0.f,0.f,0.f}, a1 = a0;
        #pragma unroll 8
        for (int k = 0; k < 512; k += 32)
            a0 = __builtin_amdgcn_mfma_f32_16x16x32_bf16(
                *reinterpret_cast<const bf16x8*>(ap + k),
                *reinterpret_cast<const bf16x8*>(bp + k), a0, 0, 0, 0);
        #pragma unroll
        for (int k = 512; k < 1056; k += 32)
            a1 = __builtin_amdgcn_mfma_f32_16x16x32_bf16(
                *reinterpret_cast<const bf16x8*>(ap + k),
                *reinterpret_cast<const bf16x8*>(bp + k), a1, 0, 0, 0);
        const int col = bn + r;
        #pragma unroll
        for (int j = 0; j < 4; ++j) {
            int m = bm + q * 4 + j;
            numd[(size_t)m * 1024 + col] = a0[j] + a1[j];
        }
    }
}

// ================= K4: fused addressing + A12 pack + t3 (R13-validated) =================
__device__ __forceinline__ void redpair_sum(float& a, float& b, volatile float* redA, volatile float* redB) {
    #pragma unroll
    for (int off = 32; off > 0; off >>= 1) { a += __shfl_down(a, off, 64); b += __shfl_down(b, off, 64); }
    int wid = threadIdx.x >> 6;
    __syncthreads();
    if ((threadIdx.x & 63) == 0) { redA[wid] = a; redB[wid] = b; }
    __syncthreads();
    a = redA[0]+redA[1]+redA[2]+redA[3]+redA[4]+redA[5]+redA[6]+redA[7];
    b = redB[0]+redB[1]+redB[2]+redB[3]+redB[4]+redB[5]+redB[6]+redB[7];
}
__device__ __forceinline__ void redpair_max(float& a, float& b, volatile float* redA, volatile float* redB) {
    #pragma unroll
    for (int off = 32; off > 0; off >>= 1) { a = fmaxf(a, __shfl_down(a, off, 64)); b = fmaxf(b, __shfl_down(b, off, 64)); }
    int wid = threadIdx.x >> 6;
    __syncthreads();
    if ((threadIdx.x & 63) == 0) { redA[wid] = a; redB[wid] = b; }
    __syncthreads();
    a = fmaxf(fmaxf(fmaxf(redA[0],redA[1]),fmaxf(redA[2],redA[3])),fmaxf(fmaxf(redA[4],redA[5]),fmaxf(redA[6],redA[7])));
    b = fmaxf(fmaxf(fmaxf(redB[0],redB[1]),fmaxf(redB[2],redB[3])),fmaxf(fmaxf(redB[4],redB[5]),fmaxf(redB[6],redB[7])));
}

__global__ __launch_bounds__(512)
void address_fused(const float* __restrict__ rpwp, const float* __restrict__ numd,
                   __hip_bfloat16* __restrict__ A12, float* __restrict__ t3)
{
    const int b = blockIdx.x;
    const int t = threadIdx.x;            // slot
    const float* pr = rpwp + (size_t)b * RW_LD;
    const float* pw = pr + W_OFF;

    __shared__ float redA[8], redB[8];
    __shared__ float bufr[SS], bufw[SS];

    float beta_r  = softplusf(pr[WD]);
    float gate_r  = sigmoidf(pr[WD + 1]);
    float r0 = pr[WD+2], r1 = pr[WD+3], r2 = pr[WD+4];
    float rmx = fmaxf(r0, fmaxf(r1, r2));
    float re0 = expf(r0-rmx), re1 = expf(r1-rmx), re2 = expf(r2-rmx);
    float rinv = 1.f / (re0+re1+re2);
    float shr0 = re0*rinv, shr1 = re1*rinv, shr2 = re2*rinv;
    float gamma_r = 1.f + softplusf(pr[WD + 5]);

    float beta_w  = softplusf(pw[WD]);
    float gate_w  = sigmoidf(pw[WD + 1]);
    float w0 = pw[WD+2], w1 = pw[WD+3], w2 = pw[WD+4];
    float wmx = fmaxf(w0, fmaxf(w1, w2));
    float we0 = expf(w0-wmx), we1 = expf(w1-wmx), we2 = expf(w2-wmx);
    float winv = 1.f / (we0+we1+we2);
    float shw0 = we0*winv, shw1 = we1*winv, shw2 = we2*winv;
    float gamma_w = 1.f + softplusf(pw[WD + 5]);

    {
        float kv = (t < WD) ? pr[t] : pw[t - WD];
        float vv = kv * kv;
        #pragma unroll
        for (int off = 32; off > 0; off >>= 1) vv += __shfl_down(vv, off, 64);
        int wid = t >> 6;
        if ((t & 63) == 0) redA[wid] = vv;
        __syncthreads();
    }
    float knr = fmaxf(sqrtf(redA[0]+redA[1]+redA[2]+redA[3]), 1e-8f);
    float knw = fmaxf(sqrtf(redA[4]+redA[5]+redA[6]+redA[7]), 1e-8f);
    __syncthreads();

    float sim_r = numd[(size_t)b * 1024 + t]       / knr * beta_r;
    float sim_w = numd[(size_t)b * 1024 + 512 + t] / knw * beta_w;

    float mr = sim_r, mw = sim_w;
    redpair_max(mr, mw, redA, redB);
    float exr = expf(sim_r - mr), exw = expf(sim_w - mw);
    float sr = exr, sw = exw;
    redpair_sum(sr, sw, redA, redB);
    float cwr = exr / sr, cww = exw / sw;

    float onehot = (t == 0) ? 1.f : 0.f;
    float gwr = gate_r * cwr + (1.f - gate_r) * onehot;
    float gww = gate_w * cww + (1.f - gate_w) * onehot;
    __syncthreads();
    bufr[t] = gwr; bufw[t] = gww;
    __syncthreads();

    int tm = (t + SS - 1) & (SS - 1), tp = (t + 1) & (SS - 1);
    float swr = shr0 * bufr[tm] + shr1 * gwr + shr2 * bufr[tp];
    float sww = shw0 * bufw[tm] + shw1 * gww + shw2 * bufw[tp];

    float spr = powf(fmaxf(swr, 0.f), gamma_r), spw = powf(fmaxf(sww, 0.f), gamma_w);
    float ssr = spr, ssw = spw;
    redpair_sum(ssr, ssw, redA, redB);
    float rfin = spr / (ssr + 1e-6f);
    float wfin = spw / (ssw + 1e-6f);

    float prod = rfin * wfin;
    A12[(size_t)b * SS + t] = __float2bfloat16(rfin);
    A12[(size_t)(256 + b) * SS + t] = __float2bfloat16(prod);
    float tp3 = prod, dummy = 0.f;
    redpair_sum(tp3, dummy, redA, redB);
    if (t == 0) t3[b] = tp3;
}

// ================= K5: t12 GEMM + rv epilogue -> rv_b (R9-proven) =================
__global__ __launch_bounds__(64)
void gemm_t12rv(const __hip_bfloat16* __restrict__ A12,
                const __hip_bfloat16* __restrict__ memT_b,
                const float* __restrict__ rpwp, const float* __restrict__ t3,
                __hip_bfloat16* __restrict__ rv_b)
{
    const int l = threadIdx.x;
    const int bn = blockIdx.x * 16;   // w
    const int bm = blockIdx.y * 16;   // b
    const int r = l & 15, q = l >> 4;
    const __hip_bfloat16* a1 = A12 + (size_t)(bm + r) * SS + q * 8;
    const __hip_bfloat16* a2 = a1 + (size_t)256 * SS;
    const __hip_bfloat16* bp = memT_b + (size_t)(bn + r) * SS + q * 8;
    f32x4 acc1 = {0.f,0.f,0.f,0.f}, acc2 = acc1;
    #pragma unroll
    for (int k = 0; k < SS; k += 32) {
        bf16x8 bb = *reinterpret_cast<const bf16x8*>(bp + k);
        acc1 = __builtin_amdgcn_mfma_f32_16x16x32_bf16(*reinterpret_cast<const bf16x8*>(a1 + k), bb, acc1, 0, 0, 0);
        acc2 = __builtin_amdgcn_mfma_f32_16x16x32_bf16(*reinterpret_cast<const bf16x8*>(a2 + k), bb, acc2, 0, 0, 0);
    }
    const int w = bn + r;
    #pragma unroll
    for (int j = 0; j < 4; ++j) {
        int b = bm + q * 4 + j;
        const float* row = rpwp + (size_t)b * RW_LD;
        float e = sigmoidf(row[W_OFF + P_READ + w]);
        float a = tanhf(row[W_OFF + P_READ + WD + w]);
        float rv = acc1[j] - e * acc2[j] + a * t3[b];
        rv_b[(size_t)b * WD + w] = __float2bfloat16(rv);
    }
}

// ================= K6: out += rv_b @ Wo_rv^T (R9-proven) =================
__global__ __launch_bounds__(64)
void gemm_outrv(const __hip_bfloat16* __restrict__ rv_b,
                const __hip_bfloat16* __restrict__ Wo_b,
                float* __restrict__ out)
{
    const int l = threadIdx.x;
    const int bn = blockIdx.x * 16;   // out col
    const int bm = blockIdx.y * 16;   // batch
    const int r = l & 15, q = l >> 4;
    const __hip_bfloat16* ap = rv_b + (size_t)(bm + r) * WD + q * 8;
    const __hip_bfloat16* bp = Wo_b + (size_t)(bn + r) * 1280 + 1024 + q * 8;
    f32x4 acc = {0.f,0.f,0.f,0.f};
    #pragma unroll
    for (int k = 0; k < WD; k += 32)
        acc = __builtin_amdgcn_mfma_f32_16x16x32_bf16(
            *reinterpret_cast<const bf16x8*>(ap + k),
            *reinterpret_cast<const bf16x8*>(bp + k), acc, 0, 0, 0);
    const int col = bn + r;
    #pragma unroll
    for (int j = 0; j < 4; ++j) {
        int m = bm + q * 4 + j;
        out[(size_t)m * OUTW + col] += acc[j];
    }
}

// ---------------- host launcher ----------------
extern "C" void kernel_launch(void* const* d_in, const int* in_sizes, int n_in,
                              void* d_out, int out_size, void* d_ws, size_t ws_size,
                              hipStream_t stream)
{
    const float* x       = (const float*)d_in[0];
    const float* W_ih    = (const float*)d_in[1];
    const float* b_ih    = (const float*)d_in[2];
    const float* b_hh    = (const float*)d_in[4];
    const float* W_read  = (const float*)d_in[5];
    const float* b_read  = (const float*)d_in[6];
    const float* W_write = (const float*)d_in[7];
    const float* b_write = (const float*)d_in[8];
    const float* W_out   = (const float*)d_in[9];
    const float* b_out   = (const float*)d_in[10];
    const float* mem     = (const float*)d_in[11];

    float* ws = (float*)d_ws;
    float* rpwp     = ws;                 // 270336
    float* numd     = ws + 270336;        // 262144 ([256][1024])
    float* t3       = ws + 532480;        // 256
    float* mem_norm = ws + 532736;        // 512
    float* bias_c   = ws + 533248;        // 3072
    float* bias_rw  = ws + 536320;        // 1056
    __hip_bfloat16* bfb = (__hip_bfloat16*)(ws + 537376);
    __hip_bfloat16* x_b    = bfb;                 // 131072
    __hip_bfloat16* Wih_c  = bfb + 131072;        // 1572864
    __hip_bfloat16* Wrw_p  = bfb + 1703936;       // 1081344
    __hip_bfloat16* Wo_b   = bfb + 2785280;       // 655360
    __hip_bfloat16* mem_b  = bfb + 3440640;       // 131072
    __hip_bfloat16* memT_b = bfb + 3571712;       // 131072
    __hip_bfloat16* WkT    = bfb + 3702784;       // 524288
    __hip_bfloat16* h2     = bfb + 4227072;       // 270336
    __hip_bfloat16* M1ext  = bfb + 4497408;       // 1081344
    __hip_bfloat16* A12    = bfb + 5578752;       // 262144
    __hip_bfloat16* rv_b   = bfb + 5840896;       // 65536
    float* out = (float*)d_out;

    // K1: convert/pack + WkT gather + norms + biases
    convert_all<<<NB_CVT + SS, 256, 0, stream>>>(
        W_ih, b_ih, b_hh, W_read, b_read, W_write, b_write, W_out, x, mem,
        Wih_c, Wrw_p, Wo_b, x_b, mem_b, memT_b, WkT, bias_c, bias_rw, mem_norm);
    // K2: gates -> h2  ||  M1 build  ||  Bterm  ||  pads
    k_stage2<<<S2_TOT, 64, 0, stream>>>(x_b, Wih_c, bias_c, mem_b, WkT,
                                        b_read, b_write, mem_norm, h2, M1ext);
    // K3: rpwp || out_h || num (h2 @ M1ext^T)
    k_stage3<<<2592, 64, 0, stream>>>(h2, Wrw_p, Wo_b, M1ext, bias_rw, b_out,
                                      rpwp, out, numd);
    // K4: addressing + A12 + t3
    address_fused<<<BB, 512, 0, stream>>>(rpwp, numd, A12, t3);
    // K5: t12 GEMM + rv -> rv_b
    gemm_t12rv<<<dim3(16, 16), 64, 0, stream>>>(A12, memT_b, rpwp, t3, rv_b);
    // K6: out += rv_b @ Wo_rv^T
    gemm_outrv<<<dim3(32, 16), 64, 0, stream>>>(rv_b, Wo_b, out);
}

// Round 17
// 64.508 us; speedup vs baseline: 1.0987x; 1.0987x over previous
//
#include <hip/hip_runtime.h>
#include <hip/hip_bf16.h>
#include <math.h>

// Problem constants
#define BB   256
#define INW  512
#define HH   1024
#define OUTW 512
#define SS   512
#define WD   256
#define P_READ  262
#define P_WRITE 774
#define RW_LD   1056   // 272 (read pad) + 784 (write pad)
#define W_OFF   272

typedef __attribute__((ext_vector_type(8))) short bf16x8;
typedef __attribute__((ext_vector_type(4))) float f32x4;

__device__ __forceinline__ float sigmoidf(float x) { return 1.f / (1.f + expf(-x)); }
__device__ __forceinline__ float softplusf(float x) { return (x > 20.f) ? x : log1pf(expf(x)); }

// f32x8 -> bf16x8 (hardware v_cvt; no hand-rolled bit tricks)
__device__ __forceinline__ bf16x8 cvt8(const float* p) {
    float4 lo = *reinterpret_cast<const float4*>(p);
    float4 hi = *reinterpret_cast<const float4*>(p + 4);
    union { bf16x8 v; __hip_bfloat16 h[8]; } u;
    u.h[0] = __float2bfloat16(lo.x); u.h[1] = __float2bfloat16(lo.y);
    u.h[2] = __float2bfloat16(lo.z); u.h[3] = __float2bfloat16(lo.w);
    u.h[4] = __float2bfloat16(hi.x); u.h[5] = __float2bfloat16(hi.y);
    u.h[6] = __float2bfloat16(hi.z); u.h[7] = __float2bfloat16(hi.w);
    return u.v;
}
__device__ __forceinline__ void st_bf8(__hip_bfloat16* d, bf16x8 v) {
    *reinterpret_cast<bf16x8*>(d) = v;
}
__device__ __forceinline__ bf16x8 pack8(float a,float b,float c,float e,float f,float g,float h,float i) {
    union { bf16x8 v; __hip_bfloat16 x[8]; } u;
    u.x[0]=__float2bfloat16(a); u.x[1]=__float2bfloat16(b); u.x[2]=__float2bfloat16(c); u.x[3]=__float2bfloat16(e);
    u.x[4]=__float2bfloat16(f); u.x[5]=__float2bfloat16(g); u.x[6]=__float2bfloat16(h); u.x[7]=__float2bfloat16(i);
    return u.v;
}
__device__ __forceinline__ float wave_sum(float v) {
    #pragma unroll
    for (int off = 32; off > 0; off >>= 1) v += __shfl_down(v, off, 64);
    return v;
}

// conversion segment sizes (all multiples of 8); Wih dropped (gates converts inline)
#define N_WRW (RW_LD*1024)
#define N_WO  (512*1280)
#define N_X   (256*512)
#define N_MB  (512*256)
#define N_MT  (256*512)
#define N_BIA 3072
#define N_BRW RW_LD
#define N_TOT (N_WRW+N_WO+N_X+N_MB+N_MT+N_BIA+N_BRW)
#define NB_CVT ((N_TOT/8 + 255) / 256)

// ================= K1: convert/pack (8-wide) + mem norms + biases =================
__global__ __launch_bounds__(256)
void convert_all(const float* __restrict__ b_ih, const float* __restrict__ b_hh,
                 const float* __restrict__ W_read, const float* __restrict__ b_read,
                 const float* __restrict__ W_write, const float* __restrict__ b_write,
                 const float* __restrict__ W_out, const float* __restrict__ x,
                 const float* __restrict__ mem,
                 __hip_bfloat16* __restrict__ Wrw_p, __hip_bfloat16* __restrict__ Wo_b,
                 __hip_bfloat16* __restrict__ x_b, __hip_bfloat16* __restrict__ mem_b,
                 __hip_bfloat16* __restrict__ memT_b,
                 float* __restrict__ bias_c, float* __restrict__ bias_rw,
                 float* __restrict__ mem_norm)
{
    if (blockIdx.x >= NB_CVT) {
        __shared__ float red[4];
        int s = blockIdx.x - NB_CVT;
        float v = mem[(size_t)s * WD + threadIdx.x];
        float vv = wave_sum(v * v);
        if ((threadIdx.x & 63) == 0) red[threadIdx.x >> 6] = vv;
        __syncthreads();
        if (threadIdx.x == 0)
            mem_norm[s] = fmaxf(sqrtf(red[0] + red[1] + red[2] + red[3]), 1e-8f);
        return;
    }
    long i = ((long)blockIdx.x * 256 + threadIdx.x) * 8;
    if (i >= N_TOT) return;
    if (i < N_WRW) {   // [Wr padded 272 ; Ww padded 784] x 1024
        int r = (int)(i >> 10), c = (int)(i & 1023);
        const float* src = nullptr;
        if (r < W_OFF) { if (r < P_READ) src = W_read + (size_t)r * 1024 + c; }
        else { int wr = r - W_OFF; if (wr < P_WRITE) src = W_write + (size_t)wr * 1024 + c; }
        bf16x8 v;
        if (src) v = cvt8(src);
        else v = pack8(0,0,0,0,0,0,0,0);
        st_bf8(Wrw_p + i, v);
        return;
    }
    i -= N_WRW;
    if (i < N_WO) { st_bf8(Wo_b + i, cvt8(W_out + i)); return; }
    i -= N_WO;
    if (i < N_X)  { st_bf8(x_b + i, cvt8(x + i)); return; }
    i -= N_X;
    if (i < N_MB) { st_bf8(mem_b + i, cvt8(mem + i)); return; }
    i -= N_MB;
    if (i < N_MT) {   // transpose gather
        int w = (int)(i >> 9), s = (int)(i & 511);
        const float* m0 = mem + (size_t)s * 256 + w;
        st_bf8(memT_b + i, pack8(m0[0], m0[256], m0[512], m0[768],
                                 m0[1024], m0[1280], m0[1536], m0[1792]));
        return;
    }
    i -= N_MT;
    if (i < N_BIA) {
        #pragma unroll
        for (int u = 0; u < 8; ++u) {
            long r = i + u;
            long sr = r < 1024 ? r : r + 1024;
            bias_c[r] = b_ih[sr] + b_hh[sr];
        }
        return;
    }
    i -= N_BIA;
    {
        #pragma unroll
        for (int u = 0; u < 8; ++u) {
            long r = i + u;
            float v = 0.f;
            if (r < W_OFF) { if (r < P_READ) v = b_read[r]; }
            else { long wr = r - W_OFF; if (wr < P_WRITE) v = b_write[wr]; }
            bias_rw[r] = v;
        }
    }
}

// ================= K2: gates GEMM + LSTM -> h_b (A bf16, W_ih inline cvt — each elem cvt'd once) =================
__global__ __launch_bounds__(64)
void gemm_gates(const __hip_bfloat16* __restrict__ x_b,
                const float* __restrict__ W_ih,
                const float* __restrict__ bias_c,
                __hip_bfloat16* __restrict__ h_b)
{
    const int l = threadIdx.x;
    const int bn = blockIdx.x * 16;
    const int bm = blockIdx.y * 16;
    const int r = l & 15, q = l >> 4;
    const __hip_bfloat16* ap = x_b + (size_t)(bm + r) * INW + q * 8;
    // i/g/o rows of W_ih (f-gate dead: c0=0), first 512 cols (rv0=0); row stride 768
    const float* bip = W_ih + (size_t)(bn + r) * 768 + q * 8;
    const float* bgp = W_ih + (size_t)(2048 + bn + r) * 768 + q * 8;
    const float* bop = W_ih + (size_t)(3072 + bn + r) * 768 + q * 8;
    f32x4 ai = {0.f,0.f,0.f,0.f}, ag = ai, ao = ai;
    #pragma unroll
    for (int k = 0; k < INW; k += 32) {
        bf16x8 a = *reinterpret_cast<const bf16x8*>(ap + k);
        ai = __builtin_amdgcn_mfma_f32_16x16x32_bf16(a, cvt8(bip + k), ai, 0, 0, 0);
        ag = __builtin_amdgcn_mfma_f32_16x16x32_bf16(a, cvt8(bgp + k), ag, 0, 0, 0);
        ao = __builtin_amdgcn_mfma_f32_16x16x32_bf16(a, cvt8(bop + k), ao, 0, 0, 0);
    }
    const int j = bn + r;
    const float bii = bias_c[j], big = bias_c[1024 + j], bio = bias_c[2048 + j];
    #pragma unroll
    for (int jj = 0; jj < 4; ++jj) {
        int b = bm + q * 4 + jj;
        float c = sigmoidf(ai[jj] + bii) * tanhf(ag[jj] + big);
        h_b[(size_t)b * HH + j] = __float2bfloat16(sigmoidf(ao[jj] + bio) * tanhf(c));
    }
}

// ================= K3: dual GEMM (rpwp + keys harvest || out h-part) — R9-proven =================
__global__ __launch_bounds__(64)
void gemm_dual(const __hip_bfloat16* __restrict__ h_b,
               const __hip_bfloat16* __restrict__ Wrw_p,
               const __hip_bfloat16* __restrict__ Wo_b,
               const float* __restrict__ bias_rw, const float* __restrict__ b_out,
               float* __restrict__ rpwp, float* __restrict__ out,
               __hip_bfloat16* __restrict__ keys)
{
    const int bid = blockIdx.x;
    const int lane = threadIdx.x;
    const int r = lane & 15, q = lane >> 4;
    int bm, bn, ldb;
    const __hip_bfloat16* B;
    if (bid < 1056) { int nt = bid % 66, mt = bid / 66; bm = mt * 16; bn = nt * 16; B = Wrw_p; ldb = HH; }
    else { int o = bid - 1056; int nt = o & 31, mt = o >> 5; bm = mt * 16; bn = nt * 16; B = Wo_b; ldb = 1280; }

    const __hip_bfloat16* ap = h_b + (size_t)(bm + r) * HH + q * 8;
    const __hip_bfloat16* bp = B + (size_t)(bn + r) * ldb + q * 8;
    f32x4 a0 = {0.f,0.f,0.f,0.f}, a1 = a0;
    #pragma unroll 8
    for (int k = 0; k < 512; k += 32) {
        a0 = __builtin_amdgcn_mfma_f32_16x16x32_bf16(
            *reinterpret_cast<const bf16x8*>(ap + k),
            *reinterpret_cast<const bf16x8*>(bp + k), a0, 0, 0, 0);
        a1 = __builtin_amdgcn_mfma_f32_16x16x32_bf16(
            *reinterpret_cast<const bf16x8*>(ap + 512 + k),
            *reinterpret_cast<const bf16x8*>(bp + 512 + k), a1, 0, 0, 0);
    }
    const int col = bn + r;
    if (bid < 1056) {
        const float bv = bias_rw[col];
        #pragma unroll
        for (int j = 0; j < 4; ++j) {
            int m = bm + q * 4 + j;
            float v = a0[j] + a1[j] + bv;
            rpwp[(size_t)m * RW_LD + col] = v;
            // keys: rows 0..255 = read keys, rows 256..511 = write keys
            if (col < WD)
                keys[(size_t)m * WD + col] = __float2bfloat16(v);
            else if (col >= W_OFF && col < W_OFF + WD)
                keys[(size_t)(256 + m) * WD + (col - W_OFF)] = __float2bfloat16(v);
        }
    } else {
        const float bv = b_out[col];
        #pragma unroll
        for (int j = 0; j < 4; ++j) {
            int m = bm + q * 4 + j;
            out[(size_t)m * OUTW + col] = a0[j] + a1[j] + bv;
        }
    }
}

// ================= K4: num GEMM [512x512] = keys @ mem^T, * (1/mem_norm[col]) — R9-proven =================
__global__ __launch_bounds__(64)
void gemm_num(const __hip_bfloat16* __restrict__ keys,
              const __hip_bfloat16* __restrict__ mem_b,
              const float* __restrict__ mem_norm,
              float* __restrict__ numd)
{
    const int l = threadIdx.x;
    const int bn = blockIdx.x * 16;   // slot
    const int bm = blockIdx.y * 16;   // key row
    const int r = l & 15, q = l >> 4;
    const __hip_bfloat16* ap = keys + (size_t)(bm + r) * WD + q * 8;
    const __hip_bfloat16* bp = mem_b + (size_t)(bn + r) * WD + q * 8;
    f32x4 acc = {0.f,0.f,0.f,0.f};
    #pragma unroll
    for (int k = 0; k < WD; k += 32)
        acc = __builtin_amdgcn_mfma_f32_16x16x32_bf16(
            *reinterpret_cast<const bf16x8*>(ap + k),
            *reinterpret_cast<const bf16x8*>(bp + k), acc, 0, 0, 0);
    const int col = bn + r;
    const float inv = 1.f / mem_norm[col];
    #pragma unroll
    for (int j = 0; j < 4; ++j)
        numd[(size_t)(bm + q * 4 + j) * SS + col] = acc[j] * inv;
}

// ================= K5: fused addressing + A12 pack + t3 — R9-proven =================
__device__ __forceinline__ void redpair_sum(float& a, float& b, volatile float* redA, volatile float* redB) {
    #pragma unroll
    for (int off = 32; off > 0; off >>= 1) { a += __shfl_down(a, off, 64); b += __shfl_down(b, off, 64); }
    int wid = threadIdx.x >> 6;
    __syncthreads();
    if ((threadIdx.x & 63) == 0) { redA[wid] = a; redB[wid] = b; }
    __syncthreads();
    a = redA[0]+redA[1]+redA[2]+redA[3]+redA[4]+redA[5]+redA[6]+redA[7];
    b = redB[0]+redB[1]+redB[2]+redB[3]+redB[4]+redB[5]+redB[6]+redB[7];
}
__device__ __forceinline__ void redpair_max(float& a, float& b, volatile float* redA, volatile float* redB) {
    #pragma unroll
    for (int off = 32; off > 0; off >>= 1) { a = fmaxf(a, __shfl_down(a, off, 64)); b = fmaxf(b, __shfl_down(b, off, 64)); }
    int wid = threadIdx.x >> 6;
    __syncthreads();
    if ((threadIdx.x & 63) == 0) { redA[wid] = a; redB[wid] = b; }
    __syncthreads();
    a = fmaxf(fmaxf(fmaxf(redA[0],redA[1]),fmaxf(redA[2],redA[3])),fmaxf(fmaxf(redA[4],redA[5]),fmaxf(redA[6],redA[7])));
    b = fmaxf(fmaxf(fmaxf(redB[0],redB[1]),fmaxf(redB[2],redB[3])),fmaxf(fmaxf(redB[4],redB[5]),fmaxf(redB[6],redB[7])));
}

__global__ __launch_bounds__(512)
void address_fused(const float* __restrict__ rpwp, const float* __restrict__ numd,
                   __hip_bfloat16* __restrict__ A12, float* __restrict__ t3)
{
    const int b = blockIdx.x;
    const int t = threadIdx.x;            // slot
    const float* pr = rpwp + (size_t)b * RW_LD;
    const float* pw = pr + W_OFF;

    __shared__ float redA[8], redB[8];
    __shared__ float bufr[SS], bufw[SS];

    float beta_r  = softplusf(pr[WD]);
    float gate_r  = sigmoidf(pr[WD + 1]);
    float r0 = pr[WD+2], r1 = pr[WD+3], r2 = pr[WD+4];
    float rmx = fmaxf(r0, fmaxf(r1, r2));
    float re0 = expf(r0-rmx), re1 = expf(r1-rmx), re2 = expf(r2-rmx);
    float rinv = 1.f / (re0+re1+re2);
    float shr0 = re0*rinv, shr1 = re1*rinv, shr2 = re2*rinv;
    float gamma_r = 1.f + softplusf(pr[WD + 5]);

    float beta_w  = softplusf(pw[WD]);
    float gate_w  = sigmoidf(pw[WD + 1]);
    float w0 = pw[WD+2], w1 = pw[WD+3], w2 = pw[WD+4];
    float wmx = fmaxf(w0, fmaxf(w1, w2));
    float we0 = expf(w0-wmx), we1 = expf(w1-wmx), we2 = expf(w2-wmx);
    float winv = 1.f / (we0+we1+we2);
    float shw0 = we0*winv, shw1 = we1*winv, shw2 = we2*winv;
    float gamma_w = 1.f + softplusf(pw[WD + 5]);

    {
        float kv = (t < WD) ? pr[t] : pw[t - WD];
        float vv = kv * kv;
        #pragma unroll
        for (int off = 32; off > 0; off >>= 1) vv += __shfl_down(vv, off, 64);
        int wid = t >> 6;
        if ((t & 63) == 0) redA[wid] = vv;
        __syncthreads();
    }
    float knr = fmaxf(sqrtf(redA[0]+redA[1]+redA[2]+redA[3]), 1e-8f);
    float knw = fmaxf(sqrtf(redA[4]+redA[5]+redA[6]+redA[7]), 1e-8f);
    __syncthreads();

    float sim_r = numd[(size_t)b * SS + t]         / knr * beta_r;
    float sim_w = numd[(size_t)(256 + b) * SS + t] / knw * beta_w;

    float mr = sim_r, mw = sim_w;
    redpair_max(mr, mw, redA, redB);
    float exr = expf(sim_r - mr), exw = expf(sim_w - mw);
    float sr = exr, sw = exw;
    redpair_sum(sr, sw, redA, redB);
    float cwr = exr / sr, cww = exw / sw;

    float onehot = (t == 0) ? 1.f : 0.f;
    float gwr = gate_r * cwr + (1.f - gate_r) * onehot;
    float gww = gate_w * cww + (1.f - gate_w) * onehot;
    __syncthreads();
    bufr[t] = gwr; bufw[t] = gww;
    __syncthreads();

    int tm = (t + SS - 1) & (SS - 1), tp = (t + 1) & (SS - 1);
    float swr = shr0 * bufr[tm] + shr1 * gwr + shr2 * bufr[tp];
    float sww = shw0 * bufw[tm] + shw1 * gww + shw2 * bufw[tp];

    float spr = powf(fmaxf(swr, 0.f), gamma_r), spw = powf(fmaxf(sww, 0.f), gamma_w);
    float ssr = spr, ssw = spw;
    redpair_sum(ssr, ssw, redA, redB);
    float rfin = spr / (ssr + 1e-6f);
    float wfin = spw / (ssw + 1e-6f);

    float prod = rfin * wfin;
    A12[(size_t)b * SS + t] = __float2bfloat16(rfin);
    A12[(size_t)(256 + b) * SS + t] = __float2bfloat16(prod);
    float tp3 = prod, dummy = 0.f;
    redpair_sum(tp3, dummy, redA, redB);
    if (t == 0) t3[b] = tp3;
}

// ================= K6: t12 GEMM + rv epilogue -> rv_b — R9-proven =================
__global__ __launch_bounds__(64)
void gemm_t12rv(const __hip_bfloat16* __restrict__ A12,
                const __hip_bfloat16* __restrict__ memT_b,
                const float* __restrict__ rpwp, const float* __restrict__ t3,
                __hip_bfloat16* __restrict__ rv_b)
{
    const int l = threadIdx.x;
    const int bn = blockIdx.x * 16;   // w
    const int bm = blockIdx.y * 16;   // b
    const int r = l & 15, q = l >> 4;
    const __hip_bfloat16* a1 = A12 + (size_t)(bm + r) * SS + q * 8;
    const __hip_bfloat16* a2 = a1 + (size_t)256 * SS;
    const __hip_bfloat16* bp = memT_b + (size_t)(bn + r) * SS + q * 8;
    f32x4 acc1 = {0.f,0.f,0.f,0.f}, acc2 = acc1;
    #pragma unroll
    for (int k = 0; k < SS; k += 32) {
        bf16x8 bb = *reinterpret_cast<const bf16x8*>(bp + k);
        acc1 = __builtin_amdgcn_mfma_f32_16x16x32_bf16(*reinterpret_cast<const bf16x8*>(a1 + k), bb, acc1, 0, 0, 0);
        acc2 = __builtin_amdgcn_mfma_f32_16x16x32_bf16(*reinterpret_cast<const bf16x8*>(a2 + k), bb, acc2, 0, 0, 0);
    }
    const int w = bn + r;
    #pragma unroll
    for (int j = 0; j < 4; ++j) {
        int b = bm + q * 4 + j;
        const float* row = rpwp + (size_t)b * RW_LD;
        float e = sigmoidf(row[W_OFF + P_READ + w]);
        float a = tanhf(row[W_OFF + P_READ + WD + w]);
        float rv = acc1[j] - e * acc2[j] + a * t3[b];
        rv_b[(size_t)b * WD + w] = __float2bfloat16(rv);
    }
}

// ================= K7: out += rv_b @ Wo_rv^T — R9-proven =================
__global__ __launch_bounds__(64)
void gemm_outrv(const __hip_bfloat16* __restrict__ rv_b,
                const __hip_bfloat16* __restrict__ Wo_b,
                float* __restrict__ out)
{
    const int l = threadIdx.x;
    const int bn = blockIdx.x * 16;   // out col
    const int bm = blockIdx.y * 16;   // batch
    const int r = l & 15, q = l >> 4;
    const __hip_bfloat16* ap = rv_b + (size_t)(bm + r) * WD + q * 8;
    const __hip_bfloat16* bp = Wo_b + (size_t)(bn + r) * 1280 + 1024 + q * 8;
    f32x4 acc = {0.f,0.f,0.f,0.f};
    #pragma unroll
    for (int k = 0; k < WD; k += 32)
        acc = __builtin_amdgcn_mfma_f32_16x16x32_bf16(
            *reinterpret_cast<const bf16x8*>(ap + k),
            *reinterpret_cast<const bf16x8*>(bp + k), acc, 0, 0, 0);
    const int col = bn + r;
    #pragma unroll
    for (int j = 0; j < 4; ++j) {
        int m = bm + q * 4 + j;
        out[(size_t)m * OUTW + col] += acc[j];
    }
}

// ---------------- host launcher ----------------
extern "C" void kernel_launch(void* const* d_in, const int* in_sizes, int n_in,
                              void* d_out, int out_size, void* d_ws, size_t ws_size,
                              hipStream_t stream)
{
    const float* x       = (const float*)d_in[0];
    const float* W_ih    = (const float*)d_in[1];
    const float* b_ih    = (const float*)d_in[2];
    const float* b_hh    = (const float*)d_in[4];
    const float* W_read  = (const float*)d_in[5];
    const float* b_read  = (const float*)d_in[6];
    const float* W_write = (const float*)d_in[7];
    const float* b_write = (const float*)d_in[8];
    const float* W_out   = (const float*)d_in[9];
    const float* b_out   = (const float*)d_in[10];
    const float* mem     = (const float*)d_in[11];

    float* ws = (float*)d_ws;
    float* rpwp     = ws;                 // 270336
    float* numd     = ws + 270336;        // 262144
    float* t3       = ws + 532480;        // 256
    float* mem_norm = ws + 532736;        // 512
    float* bias_c   = ws + 533248;        // 3072
    float* bias_rw  = ws + 536320;        // 1056
    __hip_bfloat16* bfb = (__hip_bfloat16*)(ws + 537376);
    __hip_bfloat16* x_b    = bfb;                 // 131072
    __hip_bfloat16* Wrw_p  = bfb + 131072;        // 1081344
    __hip_bfloat16* Wo_b   = bfb + 1212416;       // 655360
    __hip_bfloat16* mem_b  = bfb + 1867776;       // 131072
    __hip_bfloat16* memT_b = bfb + 1998848;       // 131072
    __hip_bfloat16* h_b    = bfb + 2129920;       // 262144
    __hip_bfloat16* keys   = bfb + 2392064;       // 131072
    __hip_bfloat16* A12    = bfb + 2523136;       // 262144
    __hip_bfloat16* rv_b   = bfb + 2785280;       // 65536
    float* out = (float*)d_out;

    // K1: convert/pack (8-wide, no Wih) + mem norms + biases
    convert_all<<<NB_CVT + SS, 256, 0, stream>>>(
        b_ih, b_hh, W_read, b_read, W_write, b_write, W_out, x, mem,
        Wrw_p, Wo_b, x_b, mem_b, memT_b, bias_c, bias_rw, mem_norm);
    // K2: gates GEMM + LSTM -> h_b (W_ih inline cvt, used once)
    gemm_gates<<<dim3(64, 16), 64, 0, stream>>>(x_b, W_ih, bias_c, h_b);
    // K3: rpwp GEMM (+keys harvest) || out h-part GEMM
    gemm_dual<<<1568, 64, 0, stream>>>(h_b, Wrw_p, Wo_b, bias_rw, b_out, rpwp, out, keys);
    // K4: num = keys @ mem^T (pre-divided by mem_norm)
    gemm_num<<<dim3(32, 32), 64, 0, stream>>>(keys, mem_b, mem_norm, numd);
    // K5: addressing + A12 + t3
    address_fused<<<BB, 512, 0, stream>>>(rpwp, numd, A12, t3);
    // K6: t12 GEMM + rv -> rv_b
    gemm_t12rv<<<dim3(16, 16), 64, 0, stream>>>(A12, memT_b, rpwp, t3, rv_b);
    // K7: out += rv_b @ Wo_rv^T
    gemm_outrv<<<dim3(32, 16), 64, 0, stream>>>(rv_b, Wo_b, out);
}